// Round 1
// baseline (479.003 us; speedup 1.0000x reference)
//
#include <hip/hip_runtime.h>
#include <math.h>

#define BB 16
#define CC 1024
#define SS 4096
#define SCH 16            // spatial positions per chunk
#define NCH 4             // chunks per block
#define SPB (SCH * NCH)   // 64 s per block
#define KBLK (SS / SPB)   // 64 k-blocks per batch

__device__ __forceinline__ float4 shfl_down_f4(float4 v, int d) {
    v.x = __shfl_down(v.x, d);
    v.y = __shfl_down(v.y, d);
    v.z = __shfl_down(v.z, d);
    v.w = __shfl_down(v.w, d);
    return v;
}
__device__ __forceinline__ void add4(float4& a, const float4 b) {
    a.x += b.x; a.y += b.y; a.z += b.z; a.w += b.w;
}

// Fused single-pass kernel, v2.
// - No online max: logits are provably tiny (|l| <~ 1), exp(l) direct.
// - ONE raw s_barrier per chunk (lgkmcnt-only wait -> prefetched global
//   loads stay in flight across the barrier, m201/T3-T4 pattern).
// - Cross-wave logit reduce done REDUNDANTLY by every thread from LDS
//   (8 broadcast ds_read_b128) -> no serialized wave-0 section, no B2.
// - wred double-buffered by chunk parity (race-free with 1 barrier/chunk).
// - Scalar np[8] (s-components collapse in the fold) frees VGPRs for
//   double-buffered x registers: chunk ch+1 loads issue before ch's barrier.
__global__ __launch_bounds__(512, 4) void k_fused(
    const float* __restrict__ x, const float* __restrict__ w,
    const float* __restrict__ bias,
    float* __restrict__ Nk, float* __restrict__ sk)
{
    __shared__ float4 wred[2][32];   // 1 KB: double-buffered wave partials

    const int kblk = blockIdx.x;   // 0..63
    const int b    = blockIdx.y;   // 0..15
    const int t    = threadIdx.x;  // 0..511
    const int wave = t >> 6;       // 0..7
    const int lane = t & 63;
    const int q    = t >> 2;       // 0..127: channel group (c = q + 128*i)
    const int m    = t & 3;        // 0..3:   s = 4m..4m+3 within chunk

    // per-thread base: row q, this block's s-window, this m's quad
    const float* xb = x + (size_t)b * CC * SS + (size_t)q * SS
                        + kblk * SPB + m * 4;

    float wreg[8];
#pragma unroll
    for (int i = 0; i < 8; ++i) wreg[i] = w[q + 128 * i];
    const float bv = bias[0];

    float np[8];
#pragma unroll
    for (int i = 0; i < 8; ++i) np[i] = 0.f;
    float s_part = 0.f;            // sum of e over this m's s-positions

    float4 A[8], B[8];

#define LOAD8(dst, ch)                                                    \
    _Pragma("unroll")                                                     \
    for (int i = 0; i < 8; ++i)                                           \
        dst[i] = *(const float4*)(xb + (size_t)i * 128 * SS + (ch) * SCH);

#define CHUNK(CUR, NXT, ch, DO_PF)                                        \
    {                                                                     \
        if (DO_PF) { LOAD8(NXT, (ch) + 1); }  /* prefetch, other buffer */\
        float4 lacc = make_float4(0.f, 0.f, 0.f, 0.f);                    \
        _Pragma("unroll")                                                 \
        for (int i = 0; i < 8; ++i) {                                     \
            lacc.x += CUR[i].x * wreg[i];                                 \
            lacc.y += CUR[i].y * wreg[i];                                 \
            lacc.z += CUR[i].z * wreg[i];                                 \
            lacc.w += CUR[i].w * wreg[i];                                 \
        }                                                                 \
        /* in-wave reduce over 16 q-slots (same m) */                     \
        add4(lacc, shfl_down_f4(lacc, 4));                                \
        add4(lacc, shfl_down_f4(lacc, 8));                                \
        add4(lacc, shfl_down_f4(lacc, 16));                               \
        add4(lacc, shfl_down_f4(lacc, 32));                               \
        if (lane < 4) wred[(ch) & 1][wave * 4 + lane] = lacc;             \
        __builtin_amdgcn_sched_barrier(0);                                \
        asm volatile("s_waitcnt lgkmcnt(0)");  /* ds_write done; vmcnt */ \
        __builtin_amdgcn_s_barrier();          /* stays in flight      */ \
        __builtin_amdgcn_sched_barrier(0);                                \
        /* every thread: redundant cross-wave reduce (broadcast reads) */ \
        float4 v0 = wred[(ch) & 1][ 0 + m];                               \
        float4 v1 = wred[(ch) & 1][ 4 + m];                               \
        float4 v2 = wred[(ch) & 1][ 8 + m];                               \
        float4 v3 = wred[(ch) & 1][12 + m];                               \
        add4(v0, wred[(ch) & 1][16 + m]);                                 \
        add4(v1, wred[(ch) & 1][20 + m]);                                 \
        add4(v2, wred[(ch) & 1][24 + m]);                                 \
        add4(v3, wred[(ch) & 1][28 + m]);                                 \
        add4(v0, v1); add4(v2, v3); add4(v0, v2);                         \
        float4 e;                                                         \
        e.x = __expf((v0.x + bv) * 0.03125f);                             \
        e.y = __expf((v0.y + bv) * 0.03125f);                             \
        e.z = __expf((v0.z + bv) * 0.03125f);                             \
        e.w = __expf((v0.w + bv) * 0.03125f);                             \
        s_part += (e.x + e.y) + (e.z + e.w);                              \
        _Pragma("unroll")                                                 \
        for (int i = 0; i < 8; ++i)                                       \
            np[i] += CUR[i].x * e.x + CUR[i].y * e.y                      \
                   + CUR[i].z * e.z + CUR[i].w * e.w;                     \
    }

    LOAD8(A, 0);
    CHUNK(A, B, 0, 1)
    CHUNK(B, A, 1, 1)
    CHUNK(A, B, 2, 1)
    CHUNK(B, A, 3, 0)

#undef CHUNK
#undef LOAD8

    // ---- epilogue: reduce np across the 4 m-lanes, write N_k[c] ----
#pragma unroll
    for (int i = 0; i < 8; ++i) {
        float v = np[i];
        v += __shfl_down(v, 1);
        v += __shfl_down(v, 2);
        if (m == 0)
            Nk[((size_t)(b * KBLK + kblk)) * CC + q + 128 * i] = v;
    }
    // s_part is identical across all q for a given m; wave 0 reduces over m
    if (t < 64) {
        float sv = s_part;
        sv += __shfl_down(sv, 1);
        sv += __shfl_down(sv, 2);
        if (t == 0) sk[b * KBLK + kblk] = sv;
    }
}

// Combine: out[b,c] = (sum_k Nk[k,c]) / (sum_k sk[k]).  No per-k weight
// (no max shift), so this is a plain coalesced column sum + one divide.
__global__ __launch_bounds__(64) void k_combine(
    const float* __restrict__ Nk, const float* __restrict__ sk,
    float* __restrict__ out)
{
    const int b  = blockIdx.y;
    const int c0 = blockIdx.x * 64;
    const int t  = threadIdx.x;

    float D = sk[b * KBLK + t];          // KBLK == 64: one k per lane
    for (int d = 32; d; d >>= 1) D += __shfl_xor(D, d);

    float acc = 0.f;
    const float* Nb = Nk + (size_t)b * KBLK * CC + c0 + t;
#pragma unroll 4
    for (int k = 0; k < KBLK; ++k)
        acc += Nb[(size_t)k * CC];
    out[b * CC + c0 + t] = acc / D;
}

extern "C" void kernel_launch(void* const* d_in, const int* in_sizes, int n_in,
                              void* d_out, int out_size, void* d_ws, size_t ws_size,
                              hipStream_t stream) {
    const float* x    = (const float*)d_in[0];  // [16,1024,64,64]
    const float* w    = (const float*)d_in[1];  // [1024]
    const float* bias = (const float*)d_in[2];  // [1]
    float* out = (float*)d_out;                 // [16,1024,1,1]

    float* Nk = (float*)d_ws;                           // 16*64*1024 f32 = 4 MB
    float* sk = Nk + (size_t)BB * KBLK * CC;            // 16*64 f32

    k_fused<<<dim3(KBLK, BB), 512, 0, stream>>>(x, w, bias, Nk, sk);
    k_combine<<<dim3(CC / 64, BB), 64, 0, stream>>>(Nk, sk, out);
}

// Round 2
// 450.166 us; speedup vs baseline: 1.0641x; 1.0641x over previous
//
#include <hip/hip_runtime.h>
#include <math.h>

#define BB 16
#define CC 1024
#define SS 4096
#define SCH 16            // spatial positions per chunk
#define NCH 4             // chunks per block
#define SPB (SCH * NCH)   // 64 s per block
#define KBLK (SS / SPB)   // 64 k-blocks per batch

__device__ __forceinline__ float4 shfl_down_f4(float4 v, int d) {
    v.x = __shfl_down(v.x, d);
    v.y = __shfl_down(v.y, d);
    v.z = __shfl_down(v.z, d);
    v.w = __shfl_down(v.w, d);
    return v;
}
__device__ __forceinline__ void add4(float4& a, const float4 b) {
    a.x += b.x; a.y += b.y; a.z += b.z; a.w += b.w;
}

// v3: v2's structure (no-max softmax, 1 barrier/chunk, redundant cross-wave
// reduce) WITHOUT the explicit double-buffer that spilled to scratch in v2
// (VGPR=64 + 244 MiB scratch writes). Single xv[8] buffer, 2-accumulator
// LDS reduce -> fits ~90 VGPRs under the 128 cap of launch_bounds(512,4).
__global__ __launch_bounds__(512, 4) void k_fused(
    const float* __restrict__ x, const float* __restrict__ w,
    const float* __restrict__ bias,
    float* __restrict__ Nk, float* __restrict__ sk)
{
    __shared__ float4 wred[2][32];   // 1 KB: double-buffered wave partials

    const int kblk = blockIdx.x;   // 0..63
    const int b    = blockIdx.y;   // 0..15
    const int t    = threadIdx.x;  // 0..511
    const int wave = t >> 6;       // 0..7
    const int lane = t & 63;
    const int q    = t >> 2;       // 0..127: channel group (c = q + 128*i)
    const int m    = t & 3;        // 0..3:   s = 4m..4m+3 within chunk

    const float* xb = x + (size_t)b * CC * SS + (size_t)q * SS
                        + kblk * SPB + m * 4;

    float wreg[8];
#pragma unroll
    for (int i = 0; i < 8; ++i) wreg[i] = w[q + 128 * i];
    const float bv = bias[0];

    float np[8];
#pragma unroll
    for (int i = 0; i < 8; ++i) np[i] = 0.f;
    float s_part = 0.f;

    float4 xv[8];

#define LOAD8(ch)                                                         \
    _Pragma("unroll")                                                     \
    for (int i = 0; i < 8; ++i)                                           \
        xv[i] = *(const float4*)(xb + (size_t)i * 128 * SS + (ch) * SCH);

#define CHUNK(ch, DO_NEXT)                                                \
    {                                                                     \
        float4 lacc = make_float4(0.f, 0.f, 0.f, 0.f);                    \
        _Pragma("unroll")                                                 \
        for (int i = 0; i < 8; ++i) {                                     \
            lacc.x += xv[i].x * wreg[i];                                  \
            lacc.y += xv[i].y * wreg[i];                                  \
            lacc.z += xv[i].z * wreg[i];                                  \
            lacc.w += xv[i].w * wreg[i];                                  \
        }                                                                 \
        add4(lacc, shfl_down_f4(lacc, 4));                                \
        add4(lacc, shfl_down_f4(lacc, 8));                                \
        add4(lacc, shfl_down_f4(lacc, 16));                               \
        add4(lacc, shfl_down_f4(lacc, 32));                               \
        if (lane < 4) wred[(ch) & 1][wave * 4 + lane] = lacc;             \
        __builtin_amdgcn_sched_barrier(0);                                \
        asm volatile("s_waitcnt lgkmcnt(0)");                             \
        __builtin_amdgcn_s_barrier();                                     \
        __builtin_amdgcn_sched_barrier(0);                                \
        /* redundant cross-wave reduce: 8 broadcast ds_read_b128 */       \
        float4 r0 = wred[(ch) & 1][ 0 + m];                               \
        float4 r1 = wred[(ch) & 1][ 4 + m];                               \
        add4(r0, wred[(ch) & 1][ 8 + m]);                                 \
        add4(r1, wred[(ch) & 1][12 + m]);                                 \
        add4(r0, wred[(ch) & 1][16 + m]);                                 \
        add4(r1, wred[(ch) & 1][20 + m]);                                 \
        add4(r0, wred[(ch) & 1][24 + m]);                                 \
        add4(r1, wred[(ch) & 1][28 + m]);                                 \
        add4(r0, r1);                                                     \
        float4 e;                                                         \
        e.x = __expf((r0.x + bv) * 0.03125f);                             \
        e.y = __expf((r0.y + bv) * 0.03125f);                             \
        e.z = __expf((r0.z + bv) * 0.03125f);                             \
        e.w = __expf((r0.w + bv) * 0.03125f);                             \
        s_part += (e.x + e.y) + (e.z + e.w);                              \
        _Pragma("unroll")                                                 \
        for (int i = 0; i < 8; ++i)                                       \
            np[i] += xv[i].x * e.x + xv[i].y * e.y                        \
                   + xv[i].z * e.z + xv[i].w * e.w;                       \
        if (DO_NEXT) { LOAD8((ch) + 1); }  /* earliest legal point */     \
    }

    LOAD8(0);
    CHUNK(0, 1)
    CHUNK(1, 1)
    CHUNK(2, 1)
    CHUNK(3, 0)

#undef CHUNK
#undef LOAD8

    // ---- epilogue: reduce np across the 4 m-lanes, write N_k[c] ----
#pragma unroll
    for (int i = 0; i < 8; ++i) {
        float v = np[i];
        v += __shfl_down(v, 1);
        v += __shfl_down(v, 2);
        if (m == 0)
            Nk[((size_t)(b * KBLK + kblk)) * CC + q + 128 * i] = v;
    }
    if (t < 64) {
        float sv = s_part;
        sv += __shfl_down(sv, 1);
        sv += __shfl_down(sv, 2);
        if (t == 0) sk[b * KBLK + kblk] = sv;
    }
}

// Combine: out[b,c] = (sum_k Nk[k,c]) / (sum_k sk[k]).
__global__ __launch_bounds__(64) void k_combine(
    const float* __restrict__ Nk, const float* __restrict__ sk,
    float* __restrict__ out)
{
    const int b  = blockIdx.y;
    const int c0 = blockIdx.x * 64;
    const int t  = threadIdx.x;

    float D = sk[b * KBLK + t];          // KBLK == 64: one k per lane
    for (int d = 32; d; d >>= 1) D += __shfl_xor(D, d);

    float acc = 0.f;
    const float* Nb = Nk + (size_t)b * KBLK * CC + c0 + t;
#pragma unroll 4
    for (int k = 0; k < KBLK; ++k)
        acc += Nb[(size_t)k * CC];
    out[b * CC + c0 + t] = acc / D;
}

extern "C" void kernel_launch(void* const* d_in, const int* in_sizes, int n_in,
                              void* d_out, int out_size, void* d_ws, size_t ws_size,
                              hipStream_t stream) {
    const float* x    = (const float*)d_in[0];  // [16,1024,64,64]
    const float* w    = (const float*)d_in[1];  // [1024]
    const float* bias = (const float*)d_in[2];  // [1]
    float* out = (float*)d_out;                 // [16,1024,1,1]

    float* Nk = (float*)d_ws;                           // 16*64*1024 f32 = 4 MB
    float* sk = Nk + (size_t)BB * KBLK * CC;            // 16*64 f32

    k_fused<<<dim3(KBLK, BB), 512, 0, stream>>>(x, w, bias, Nk, sk);
    k_combine<<<dim3(CC / 64, BB), 64, 0, stream>>>(Nk, sk, out);
}

// Round 3
// 374.743 us; speedup vs baseline: 1.2782x; 1.2013x over previous
//
#include <hip/hip_runtime.h>
#include <math.h>

#define BB 16
#define CC 1024
#define SS 4096
#define SCH 16            // spatial positions per chunk
#define NCH 4             // chunks per block
#define SPB (SCH * NCH)   // 64 s per block
#define KBLK (SS / SPB)   // 64 k-blocks per batch

__device__ __forceinline__ float4 shfl_down_f4(float4 v, int d) {
    v.x = __shfl_down(v.x, d);
    v.y = __shfl_down(v.y, d);
    v.z = __shfl_down(v.z, d);
    v.w = __shfl_down(v.w, d);
    return v;
}
__device__ __forceinline__ void add4(float4& a, const float4 b) {
    a.x += b.x; a.y += b.y; a.z += b.z; a.w += b.w;
}

// v4 == v3 with ONE change: __launch_bounds__(512, 2) instead of (512, 4).
// rocprof showed (512,4) forces a 64-VGPR cap (32 waves/CU) -> the x tiles
// spill to scratch: 228 MiB of scratch writes + ~100 MiB re-reads per
// dispatch (WRITE_SIZE 233 MB vs the 4 MB the kernel actually stores).
// (512,2) -> 16 waves/CU -> 128-VGPR cap; ~100 live regs fit, zero spill.
__global__ __launch_bounds__(512, 2) void k_fused(
    const float* __restrict__ x, const float* __restrict__ w,
    const float* __restrict__ bias,
    float* __restrict__ Nk, float* __restrict__ sk)
{
    __shared__ float4 wred[2][32];   // 1 KB: double-buffered wave partials

    const int kblk = blockIdx.x;   // 0..63
    const int b    = blockIdx.y;   // 0..15
    const int t    = threadIdx.x;  // 0..511
    const int wave = t >> 6;       // 0..7
    const int lane = t & 63;
    const int q    = t >> 2;       // 0..127: channel group (c = q + 128*i)
    const int m    = t & 3;        // 0..3:   s = 4m..4m+3 within chunk

    const float* xb = x + (size_t)b * CC * SS + (size_t)q * SS
                        + kblk * SPB + m * 4;

    float wreg[8];
#pragma unroll
    for (int i = 0; i < 8; ++i) wreg[i] = w[q + 128 * i];
    const float bv = bias[0];

    float np[8];
#pragma unroll
    for (int i = 0; i < 8; ++i) np[i] = 0.f;
    float s_part = 0.f;

    float4 xv[8];

#define LOAD8(ch)                                                         \
    _Pragma("unroll")                                                     \
    for (int i = 0; i < 8; ++i)                                           \
        xv[i] = *(const float4*)(xb + (size_t)i * 128 * SS + (ch) * SCH);

#define CHUNK(ch, DO_NEXT)                                                \
    {                                                                     \
        float4 lacc = make_float4(0.f, 0.f, 0.f, 0.f);                    \
        _Pragma("unroll")                                                 \
        for (int i = 0; i < 8; ++i) {                                     \
            lacc.x += xv[i].x * wreg[i];                                  \
            lacc.y += xv[i].y * wreg[i];                                  \
            lacc.z += xv[i].z * wreg[i];                                  \
            lacc.w += xv[i].w * wreg[i];                                  \
        }                                                                 \
        add4(lacc, shfl_down_f4(lacc, 4));                                \
        add4(lacc, shfl_down_f4(lacc, 8));                                \
        add4(lacc, shfl_down_f4(lacc, 16));                               \
        add4(lacc, shfl_down_f4(lacc, 32));                               \
        if (lane < 4) wred[(ch) & 1][wave * 4 + lane] = lacc;             \
        __builtin_amdgcn_sched_barrier(0);                                \
        asm volatile("s_waitcnt lgkmcnt(0)");                             \
        __builtin_amdgcn_s_barrier();                                     \
        __builtin_amdgcn_sched_barrier(0);                                \
        /* redundant cross-wave reduce: 8 broadcast ds_read_b128 */       \
        float4 r0 = wred[(ch) & 1][ 0 + m];                               \
        float4 r1 = wred[(ch) & 1][ 4 + m];                               \
        add4(r0, wred[(ch) & 1][ 8 + m]);                                 \
        add4(r1, wred[(ch) & 1][12 + m]);                                 \
        add4(r0, wred[(ch) & 1][16 + m]);                                 \
        add4(r1, wred[(ch) & 1][20 + m]);                                 \
        add4(r0, wred[(ch) & 1][24 + m]);                                 \
        add4(r1, wred[(ch) & 1][28 + m]);                                 \
        add4(r0, r1);                                                     \
        float4 e;                                                         \
        e.x = __expf((r0.x + bv) * 0.03125f);                             \
        e.y = __expf((r0.y + bv) * 0.03125f);                             \
        e.z = __expf((r0.z + bv) * 0.03125f);                             \
        e.w = __expf((r0.w + bv) * 0.03125f);                             \
        s_part += (e.x + e.y) + (e.z + e.w);                              \
        _Pragma("unroll")                                                 \
        for (int i = 0; i < 8; ++i)                                       \
            np[i] += xv[i].x * e.x + xv[i].y * e.y                        \
                   + xv[i].z * e.z + xv[i].w * e.w;                       \
        if (DO_NEXT) { LOAD8((ch) + 1); }  /* earliest legal point */     \
    }

    LOAD8(0);
    CHUNK(0, 1)
    CHUNK(1, 1)
    CHUNK(2, 1)
    CHUNK(3, 0)

#undef CHUNK
#undef LOAD8

    // ---- epilogue: reduce np across the 4 m-lanes, write N_k[c] ----
#pragma unroll
    for (int i = 0; i < 8; ++i) {
        float v = np[i];
        v += __shfl_down(v, 1);
        v += __shfl_down(v, 2);
        if (m == 0)
            Nk[((size_t)(b * KBLK + kblk)) * CC + q + 128 * i] = v;
    }
    if (t < 64) {
        float sv = s_part;
        sv += __shfl_down(sv, 1);
        sv += __shfl_down(sv, 2);
        if (t == 0) sk[b * KBLK + kblk] = sv;
    }
}

// Combine: out[b,c] = (sum_k Nk[k,c]) / (sum_k sk[k]).
__global__ __launch_bounds__(64) void k_combine(
    const float* __restrict__ Nk, const float* __restrict__ sk,
    float* __restrict__ out)
{
    const int b  = blockIdx.y;
    const int c0 = blockIdx.x * 64;
    const int t  = threadIdx.x;

    float D = sk[b * KBLK + t];          // KBLK == 64: one k per lane
    for (int d = 32; d; d >>= 1) D += __shfl_xor(D, d);

    float acc = 0.f;
    const float* Nb = Nk + (size_t)b * KBLK * CC + c0 + t;
#pragma unroll 4
    for (int k = 0; k < KBLK; ++k)
        acc += Nb[(size_t)k * CC];
    out[b * CC + c0 + t] = acc / D;
}

extern "C" void kernel_launch(void* const* d_in, const int* in_sizes, int n_in,
                              void* d_out, int out_size, void* d_ws, size_t ws_size,
                              hipStream_t stream) {
    const float* x    = (const float*)d_in[0];  // [16,1024,64,64]
    const float* w    = (const float*)d_in[1];  // [1024]
    const float* bias = (const float*)d_in[2];  // [1]
    float* out = (float*)d_out;                 // [16,1024,1,1]

    float* Nk = (float*)d_ws;                           // 16*64*1024 f32 = 4 MB
    float* sk = Nk + (size_t)BB * KBLK * CC;            // 16*64 f32

    k_fused<<<dim3(KBLK, BB), 512, 0, stream>>>(x, w, bias, Nk, sk);
    k_combine<<<dim3(CC / 64, BB), 64, 0, stream>>>(Nk, sk, out);
}